// Round 7
// baseline (53.832 us; speedup 1.0000x reference)
//
#include <hip/hip_runtime.h>

#define NATOMS 512
#define N2 (NATOMS*NATOMS)
#define NKPT 32
#define NPOLY 12
#define NSP 4
#define NSMAX 96            // K padded to 3 x 32 (81 real + sentinels)
#define TJ 64
#define NTHREADS 256
#define VSTR 49             // Vtd row stride in dwords; gcd(49,32)=1 -> 2-way max on b32

typedef __attribute__((ext_vector_type(8))) short bf16x8;
typedef __attribute__((ext_vector_type(4))) float f32x4;

static __device__ __forceinline__ unsigned f2bf2(float lo, float hi) {
    union { float f; unsigned u; } a, b; a.f = lo; b.f = hi;
    unsigned ra = a.u + 0x7FFFu + ((a.u >> 16) & 1u);   // RNE bf16
    unsigned rb = b.u + 0x7FFFu + ((b.u >> 16) & 1u);
    return (ra >> 16) | (rb & 0xFFFF0000u);
}

// ---- kernel 0: permute shifts near-first / big-last, sentinel-pad to 96 ----
__global__ void prep_shifts(const float* __restrict__ shifts,
                            float4* __restrict__ shp4, int ns)
{
    __shared__ unsigned char big[NSMAX];
    int t = threadIdx.x;                  // 128 threads
    bool isbig = false;
    float x = 0.f, y = 0.f, z = 0.f;
    if (t < ns) {
        x = shifts[t*3]; y = shifts[t*3+1]; z = shifts[t*3+2];
        isbig = (fabsf(x) > 7.5f) || (fabsf(y) > 7.5f) || (fabsf(z) > 7.5f);
    }
    if (t < NSMAX) big[t] = (t < ns && isbig) ? 1 : 0;
    __syncthreads();
    if (t < ns) {
        int nnear = 0, rank = 0;
        unsigned char me = isbig ? 1 : 0;
        for (int s = 0; s < ns; ++s) {
            nnear += (big[s] == 0);
            rank  += (s < t) && (big[s] == me);
        }
        int pos = isbig ? (nnear + rank) : rank;
        shp4[pos] = make_float4(x, y, z, 0.f);
    } else if (t < NSMAX) {
        shp4[t] = make_float4(1e9f, 1e9f, 1e9f, 0.f);   // sentinel
    }
}

// ---- kernel 1: phase table Ttg[64][96] bf16 (permuted s order) ----
// rows 0..31: cos(2*pi*(kpt[k]/5).shift[s]); rows 32..63: sin; 0 for s>=ns.
__global__ void phase_tab(const float* __restrict__ kpoints,
                          const float4* __restrict__ shp4,
                          unsigned* __restrict__ Ttg, int ns)
{
    int idx = blockIdx.x * 256 + threadIdx.x;        // 64*48 = 3072 dwords
    if (idx >= 64 * 48) return;
    int row = idx / 48, s2 = idx - row * 48;
    int k = row & 31;
    float kcx = kpoints[k*3]   * 0.2f;
    float kcy = kpoints[k*3+1] * 0.2f;
    float kcz = kpoints[k*3+2] * 0.2f;
    float val[2] = {0.f, 0.f};
    #pragma unroll
    for (int h = 0; h < 2; ++h) {
        int s = 2*s2 + h;
        if (s < ns) {
            float4 sh = shp4[s];
            float d = (kcx*sh.x + kcy*sh.y) + kcz*sh.z;
            float sn, cs;
            sincosf(6.283185307179586f * d, &sn, &cs);
            val[h] = (row >= 32) ? sn : cs;
        }
    }
    Ttg[idx] = f2bf2(val[0], val[1]);
}

// ---- kernel 2: main ----
__global__ __launch_bounds__(NTHREADS, 4)
void dftb7(const float* __restrict__ positions,
           const int* __restrict__ species,
           const float* __restrict__ param,
           const float* __restrict__ onsite,
           const float4* __restrict__ shp4,
           const unsigned short* __restrict__ Ttg,
           float* __restrict__ out)
{
    __shared__ unsigned Vtd[TJ][VSTR];        // V[pair][s] bf16, 2 per dword (12.5 KB)
    __shared__ float4 sh4s[NSMAX];            // uniform-read -> broadcast (1.5 KB)
    __shared__ float cpar4[NPOLY*NSP];        // [q][sj] for this block's si

    const int tid = threadIdx.x;
    const int bi = blockIdx.x >> 3;           // i row
    const int jt = blockIdx.x & 7;            // j octant (64 j's)
    const int si = species[bi];

    if (tid < NSMAX) sh4s[tid] = shp4[tid];
    if (tid < NPOLY*NSP) {                    // cpar4[q*4+sj]
        int q = tid >> 2, sj = tid & 3;
        cpar4[tid] = param[(si*NSP + sj)*NPOLY + q];
    }
    __syncthreads();

    const float pix = positions[bi*3], piy = positions[bi*3+1], piz = positions[bi*3+2];
    const float ons = onsite[si];

    // ---- phase A: V -> LDS. One pair/thread, wave-uniform s (execz skip) ----
    {
        const int p  = tid & 63;              // pair (local j)
        const int sq = tid >> 6;              // wave = s-quarter (24 s each)
        const int j  = jt*TJ + p;
        const float pjx = positions[j*3], pjy = positions[j*3+1], pjz = positions[j*3+2];
        const int sj = species[j];
        float c[NPOLY];
        #pragma unroll
        for (int q = 0; q < NPOLY; ++q) c[q] = cpar4[q*4 + sj];

        #pragma unroll
        for (int a = 0; a < 12; ++a) {
            float v2[2];
            #pragma unroll
            for (int h = 0; h < 2; ++h) {
                const int s = sq*24 + 2*a + h;
                float4 sh = sh4s[s];
                // numpy order: (pj + shift) - pi ; (x^2+y^2)+z^2, no FMA contraction
                float dx = (pjx + sh.x) - pix;
                float dy = (pjy + sh.y) - piy;
                float dz = (pjz + sh.z) - piz;
                float dr2 = (__fmul_rn(dx,dx) + __fmul_rn(dy,dy)) + __fmul_rn(dz,dz);
                float v_ = 0.f;
                if (dr2 <= 36.001f) {         // conservative prefilter (uniform s -> execz)
                    float dr = sqrtf(dr2);    // correctly-rounded fp32
                    if (dr > 0.1f && dr <= 6.0f) {   // exact gate
                        float x = dr * 1.8897261258369282f;
                        float y = c[NPOLY-1];
                        #pragma unroll
                        for (int q = NPOLY-2; q >= 0; --q) y = fmaf(y, x, c[q]);
                        v_ = y;
                    }
                }
                v2[h] = v_;
            }
            Vtd[p][sq*12 + a] = f2bf2(v2[0], v2[1]);   // b32, stride 49 -> <=2-way (free)
        }
    }
    __syncthreads();

    // ---- phase B: A-frags once from LDS, then per-nf B (L1-hot) + MFMA + store ----
    const int lane = tid & 63, w = tid >> 6;  // w = mfi (16-row group)
    const int r16 = lane & 15, g = lane >> 4;
    const int row = w*16 + r16;               // A row (pair)

    union { unsigned u[4]; bf16x8 v; } a0, a1, a2;
    #pragma unroll
    for (int e = 0; e < 4; ++e) {
        a0.u[e] = Vtd[row][ 0 + g*4 + e];     // s 0..31
        a1.u[e] = Vtd[row][16 + g*4 + e];     // s 32..63
        a2.u[e] = Vtd[row][32 + g*4 + e];     // s 64..95
    }
    const int jb = jt*TJ + w*16 + g*4;
    const int dons = bi - jb;                 // onsite lane-reg index if 0..3

    #pragma unroll
    for (int nf = 0; nf < 4; ++nf) {
        const int kcol = nf*16 + r16;         // 0..31 -> Hr plane, 32..63 -> Hi plane
        const unsigned short* tb = Ttg + (size_t)kcol*NSMAX + g*8;
        bf16x8 B0 = *(const bf16x8*)(tb);
        bf16x8 B1 = *(const bf16x8*)(tb + 32);
        bf16x8 B2 = *(const bf16x8*)(tb + 64);
        f32x4 acc = {0.f, 0.f, 0.f, 0.f};
        acc = __builtin_amdgcn_mfma_f32_16x16x32_bf16(a0.v, B0, acc, 0, 0, 0);
        acc = __builtin_amdgcn_mfma_f32_16x16x32_bf16(a1.v, B1, acc, 0, 0, 0);
        acc = __builtin_amdgcn_mfma_f32_16x16x32_bf16(a2.v, B2, acc, 0, 0, 0);
        // C/D layout: col(lane&15)=kcol-in-16, row(g*4+reg)=pair-in-16
        float4 v; v.x = acc[0]; v.y = acc[1]; v.z = acc[2]; v.w = acc[3];
        if (kcol < 32 && dons >= 0 && dons < 4)     // onsite on Hr diagonal
            ((float*)&v)[dons] += ons;
        *(float4*)(out + (size_t)kcol*N2 + (size_t)bi*NATOMS + jb) = v;
    }
}

extern "C" void kernel_launch(void* const* d_in, const int* in_sizes, int n_in,
                              void* d_out, int out_size, void* d_ws, size_t ws_size,
                              hipStream_t stream) {
    const float* positions = (const float*)d_in[0];
    const int*   species   = (const int*)d_in[1];
    const float* kpoints   = (const float*)d_in[2];
    const float* param     = (const float*)d_in[3];
    const float* onsite    = (const float*)d_in[4];
    const float* shifts    = (const float*)d_in[5];
    int ns = in_sizes[5] / 3;
    float* out = (float*)d_out;

    float4*   shp4 = (float4*)d_ws;                       // 96*16 = 1536 B
    unsigned* Ttg  = (unsigned*)((char*)d_ws + 2048);     // 64*96*2 = 12 KB

    prep_shifts<<<dim3(1), 128, 0, stream>>>(shifts, shp4, ns);
    phase_tab<<<dim3(12), 256, 0, stream>>>(kpoints, shp4, Ttg, ns);
    dim3 grid(NATOMS * (NATOMS/TJ));                      // 512 * 8 = 4096 blocks
    dftb7<<<grid, NTHREADS, 0, stream>>>(positions, species, param, onsite,
                                         shp4, (const unsigned short*)Ttg, out);
}